// Round 2
// baseline (3491.080 us; speedup 1.0000x reference)
//
#include <hip/hip_runtime.h>
#include <hip/hip_bf16.h>
#include <math.h>

#define NEGV -1e9f
#define NEGH -5e8f

__device__ __forceinline__ unsigned fkey(float f) {
  unsigned u = __float_as_uint(f);
  return (u & 0x80000000u) ? ~u : (u | 0x80000000u);
}
// 48-bit total-order key: (score desc, original index asc). Unique per candidate.
__device__ __forceinline__ unsigned long long key48(float s, int j) {
  return ((unsigned long long)fkey(s) << 15) | (unsigned long long)(32767 - j);
}
__device__ __forceinline__ float unkey_score(unsigned long long k) {
  unsigned u = (unsigned)(k >> 15);
  return (u & 0x80000000u) ? __uint_as_float(u & 0x7FFFFFFFu)
                           : __uint_as_float(~u);
}

// ------------------------------------------------------------------
// Conv 3x3 SAME, 512->512, as im2col SGEMM.
// feat [8,512,50,50] NCHW fp32; W1 [512,512,3,3] (flat = A[m][k], k=cin*9+dy*3+dx)
// out  NHWC [8,2500,512]
// ------------------------------------------------------------------
__global__ __launch_bounds__(256) void conv3x3_kernel(
    const float* __restrict__ feat, const float* __restrict__ W1,
    const float* __restrict__ b1, float* __restrict__ out) {
  __shared__ float As[36][132];
  __shared__ float Bs[36][128];
  const int tid = threadIdx.x;
  const int b  = blockIdx.z;
  const int m0 = blockIdx.y * 128;
  const int n0 = blockIdx.x * 128;
  const int tn = tid & 15, tm = tid >> 4;
  const int lm = tid & 127;
  const int kh = tid >> 7;
  const int ng = n0 + lm;
  const int yy = ng / 50;
  const int xx = ng - yy * 50;
  const bool npix_ok = (ng < 2500);
  const float* featb = feat + b * (512 * 2500);
  const float* arow  = W1 + (m0 + lm) * 4608;

  float acc[8][8];
  #pragma unroll
  for (int i = 0; i < 8; ++i)
    #pragma unroll
    for (int j = 0; j < 8; ++j) acc[i][j] = 0.f;

  for (int kc = 0; kc < 4608; kc += 36) {
    #pragma unroll
    for (int i = 0; i < 18; ++i) {
      int k = i * 2 + kh;
      As[k][lm] = arow[kc + k];
    }
    #pragma unroll
    for (int i = 0; i < 18; ++i) {
      int k  = i * 2 + kh;
      int kg = kc + k;
      int cin = kg / 9;
      int off = kg - cin * 9;
      int dy = off / 3;
      int dx = off - dy * 3;
      int iy = yy + dy - 1, ix = xx + dx - 1;
      float v = 0.f;
      if (npix_ok && (unsigned)iy < 50u && (unsigned)ix < 50u)
        v = featb[cin * 2500 + iy * 50 + ix];
      Bs[k][lm] = v;
    }
    __syncthreads();
    for (int k = 0; k < 36; ++k) {
      float a[8], bb[8];
      *(float4*)&a[0]  = *(const float4*)&As[k][tm * 8];
      *(float4*)&a[4]  = *(const float4*)&As[k][tm * 8 + 4];
      *(float4*)&bb[0] = *(const float4*)&Bs[k][tn * 8];
      *(float4*)&bb[4] = *(const float4*)&Bs[k][tn * 8 + 4];
      #pragma unroll
      for (int i = 0; i < 8; ++i)
        #pragma unroll
        for (int j = 0; j < 8; ++j)
          acc[i][j] = fmaf(a[i], bb[j], acc[i][j]);
    }
    __syncthreads();
  }

  float bias[8];
  *(float4*)&bias[0] = *(const float4*)&b1[m0 + tm * 8];
  *(float4*)&bias[4] = *(const float4*)&b1[m0 + tm * 8 + 4];
  for (int j = 0; j < 8; ++j) {
    int n = n0 + tn * 8 + j;
    if (n >= 2500) break;
    float* op = out + (size_t)(b * 2500 + n) * 512 + m0 + tm * 8;
    float4 v0, v1;
    v0.x = fmaxf(acc[0][j] + bias[0], 0.f); v0.y = fmaxf(acc[1][j] + bias[1], 0.f);
    v0.z = fmaxf(acc[2][j] + bias[2], 0.f); v0.w = fmaxf(acc[3][j] + bias[3], 0.f);
    v1.x = fmaxf(acc[4][j] + bias[4], 0.f); v1.y = fmaxf(acc[5][j] + bias[5], 0.f);
    v1.z = fmaxf(acc[6][j] + bias[6], 0.f); v1.w = fmaxf(acc[7][j] + bias[7], 0.f);
    *(float4*)op       = v0;
    *(float4*)(op + 4) = v1;
  }
}

// ------------------------------------------------------------------
// Heads: 54 dots over 512 ch per pixel, softmax (reference subtract-max
// form) + anchor decode + clip + size filter. 1 wave/pixel, 4 pixels/block.
// ------------------------------------------------------------------
__global__ __launch_bounds__(256) void heads_kernel(
    const float* __restrict__ conv1,
    const float* __restrict__ Wreg, const float* __restrict__ breg,
    const float* __restrict__ Wcls, const float* __restrict__ bcls,
    float* __restrict__ boxes, float* __restrict__ scores) {
  __shared__ float v[4][512];
  __shared__ float o54[4][56];
  const int tid = threadIdx.x;
  const int w = tid >> 6, lane = tid & 63;
  const int pix = blockIdx.x * 4 + w;
  const int b = pix / 2500;
  const int n = pix - b * 2500;
  const int y = n / 50, x = n - y * 50;
  const float* src = conv1 + (size_t)pix * 512;
  *(float4*)&v[w][lane * 8]     = *(const float4*)&src[lane * 8];
  *(float4*)&v[w][lane * 8 + 4] = *(const float4*)&src[lane * 8 + 4];
  __syncthreads();
  if (lane < 54) {
    const float* wrow = (lane < 36) ? (Wreg + lane * 512) : (Wcls + (lane - 36) * 512);
    float s0 = 0.f, s1 = 0.f, s2 = 0.f, s3 = 0.f;
    for (int c = 0; c < 512; c += 4) {
      float4 wv = *(const float4*)&wrow[c];
      s0 = fmaf(v[w][c],     wv.x, s0);
      s1 = fmaf(v[w][c + 1], wv.y, s1);
      s2 = fmaf(v[w][c + 2], wv.z, s2);
      s3 = fmaf(v[w][c + 3], wv.w, s3);
    }
    o54[w][lane] = (s0 + s1) + (s2 + s3) + (lane < 36 ? breg[lane] : bcls[lane - 36]);
  }
  __syncthreads();
  if (lane < 9) {
    const int a = lane;
    float d0 = o54[w][a * 4 + 0], d1 = o54[w][a * 4 + 1];
    float d2 = o54[w][a * 4 + 2], d3 = o54[w][a * 4 + 3];
    float sc0 = o54[w][36 + a * 2], sc1 = o54[w][36 + a * 2 + 1];
    float mx = fmaxf(sc0, sc1);
    float e0 = expf(sc0 - mx), e1 = expf(sc1 - mx);
    float fg = e1 / (e0 + e1);                 // reference softmax form
    const int ri = a / 3;
    const int si = a - ri * 3;
    float sv = (si == 0) ? 8.f : (si == 1 ? 16.f : 32.f);
    float sqr_r  = (ri == 0) ? 0.70710678f : (ri == 1 ? 1.f : 1.41421356f);
    float sqr_ir = (ri == 0) ? 1.41421356f : (ri == 1 ? 1.f : 0.70710678f);
    float hh = 16.f * sv * sqr_r;
    float ww = 16.f * sv * sqr_ir;
    float acy = 16.f * (float)(y + 1) - 25.f;
    float acx = 16.f * (float)(x + 1) - 25.f;
    float ay1 = acy - 0.5f * hh, ay2 = acy + 0.5f * hh;
    float ax1 = acx - 0.5f * ww, ax2 = acx + 0.5f * ww;
    float ah = ay2 - ay1, aw = ax2 - ax1;
    float cy0 = ay1 + 0.5f * ah, cx0 = ax1 + 0.5f * aw;
    float cy = d0 * ah + cy0, cx = d1 * aw + cx0;
    float bh = expf(d2) * ah, bw = expf(d3) * aw;
    float y1 = cy - 0.5f * bh, x1 = cx - 0.5f * bw;
    float y2 = cy + 0.5f * bh, x2 = cx + 0.5f * bw;
    y1 = fminf(fmaxf(y1, 0.f), 800.f); y2 = fminf(fmaxf(y2, 0.f), 800.f);
    x1 = fminf(fmaxf(x1, 0.f), 800.f); x2 = fminf(fmaxf(x2, 0.f), 800.f);
    bool ok = ((y2 - y1) >= 16.f) && ((x2 - x1) >= 16.f);
    int gi = b * 22500 + n * 9 + a;
    ((float4*)boxes)[gi] = make_float4(y1, x1, y2, x2);
    scores[gi] = (ok && fg == fg) ? fg : NEGV;
  }
}

// ------------------------------------------------------------------
// Exact top-6000 per batch: radix select on UNIQUE 48-bit keys
// (score desc, index asc) -> selected SET identical to stable top_k,
// including ties at the boundary. Storage order is arbitrary; NMS
// re-orders via the key.
// ------------------------------------------------------------------
__global__ __launch_bounds__(256) void topk_kernel(
    const float* __restrict__ scores, const float* __restrict__ boxes,
    float* __restrict__ tsc, float* __restrict__ tbx, int* __restrict__ tidx) {
  const int b = blockIdx.x, tid = threadIdx.x;
  __shared__ unsigned hist[256];
  __shared__ unsigned long long sh_pref;
  __shared__ unsigned sh_rem, sh_cnt;
  const float* sc = scores + b * 22500;
  if (tid == 0) { sh_pref = 0ull; sh_rem = 6000u; }
  __syncthreads();
  for (int pass = 0; pass < 6; ++pass) {
    const int shift = 40 - pass * 8;
    hist[tid] = 0u;
    __syncthreads();
    const unsigned long long pref = sh_pref;
    for (int j = tid; j < 22500; j += 256) {
      unsigned long long key = key48(sc[j], j);
      if ((key >> (shift + 8)) == pref)
        atomicAdd(&hist[(unsigned)(key >> shift) & 255u], 1u);
    }
    __syncthreads();
    if (tid == 0) {
      unsigned rem = sh_rem;
      unsigned c = 0; int sel = 0;
      for (int bin = 255; bin >= 0; --bin) {
        unsigned nc = c + hist[bin];
        if (nc >= rem) { sel = bin; break; }
        c = nc;
      }
      sh_rem = rem - c;
      sh_pref = (sh_pref << 8) | (unsigned long long)sel;
    }
    __syncthreads();
  }
  const unsigned long long T = sh_pref;   // 6000th-largest key (unique keys)
  if (tid == 0) sh_cnt = 0u;
  __syncthreads();
  const float4* bx4 = (const float4*)boxes;
  float4* tb4 = (float4*)tbx;
  for (int j = tid; j < 22500; j += 256) {
    unsigned long long key = key48(sc[j], j);
    if (key >= T) {
      unsigned slot = atomicAdd(&sh_cnt, 1u);
      if (slot < 6000u) {
        tsc[b * 6000 + slot] = sc[j];
        tidx[b * 6000 + slot] = j;
        tb4[b * 6000 + slot] = bx4[b * 22500 + j];
      }
    }
  }
}

// ------------------------------------------------------------------
// Greedy NMS, one block/batch. Candidate state = 48-bit key in LDS;
// argmax over keys == reference argmax over stable-sorted scores
// (score desc, original index asc). Suppressed -> key 0.
// ------------------------------------------------------------------
__global__ __launch_bounds__(512) void nms_kernel(
    const float* __restrict__ tsc, const float* __restrict__ tbx,
    const int* __restrict__ tidx, float* __restrict__ out) {
  const int b = blockIdx.x, tid = threadIdx.x;
  __shared__ unsigned long long kk[6000];
  __shared__ unsigned long long wk[8];
  __shared__ int wslot[8];
  __shared__ float cur_s, cur_y1, cur_x1, cur_y2, cur_x2, cur_a;
  __shared__ int cur_slot;
  const float4* boxes = (const float4*)tbx + (size_t)b * 6000;
  const float* scs = tsc + b * 6000;
  const int* idxs = tidx + b * 6000;
  for (int j = tid; j < 6000; j += 512)
    kk[j] = key48(scs[j], idxs[j]);
  __syncthreads();

  unsigned long long bk = 0ull; int bs = 0;
  for (int j = tid; j < 6000; j += 512) {
    unsigned long long k = kk[j];
    if (k > bk) { bk = k; bs = j; }
  }
  #pragma unroll
  for (int off = 32; off > 0; off >>= 1) {
    unsigned long long ok_ = __shfl_down(bk, off);
    int os = __shfl_down(bs, off);
    if (ok_ > bk) { bk = ok_; bs = os; }
  }
  if ((tid & 63) == 0) { wk[tid >> 6] = bk; wslot[tid >> 6] = bs; }
  __syncthreads();
  if (tid == 0) {
    unsigned long long v = wk[0]; int s = wslot[0];
    for (int k2 = 1; k2 < 8; ++k2)
      if (wk[k2] > v) { v = wk[k2]; s = wslot[k2]; }
    float4 bb = boxes[s];
    cur_s = unkey_score(v); cur_slot = s;
    cur_y1 = bb.x; cur_x1 = bb.y; cur_y2 = bb.z; cur_x2 = bb.w;
    cur_a = (bb.z - bb.x) * (bb.w - bb.y);
  }
  __syncthreads();

  float* rois = out;            // [8][300][5]
  float* rsc  = out + 12000;    // [8][300]
  for (int t = 0; t < 300; ++t) {
    const float cs = cur_s, cy1 = cur_y1, cx1 = cur_x1, cy2 = cur_y2, cx2 = cur_x2, ca = cur_a;
    const int ci = cur_slot;
    if (!(cs > NEGH)) {         // exhausted (or NaN sentinel): zeros
      for (int r = t + tid; r < 300; r += 512) {
        float* rp = rois + (size_t)(b * 300 + r) * 5;
        rp[0] = 0.f; rp[1] = 0.f; rp[2] = 0.f; rp[3] = 0.f; rp[4] = 0.f;
        rsc[b * 300 + r] = 0.f;
      }
      break;
    }
    bk = 0ull; bs = 0;
    for (int j = tid; j < 6000; j += 512) {
      unsigned long long k = kk[j];
      if (k != 0ull) {
        if (j == ci) { kk[j] = 0ull; k = 0ull; }
        else {
          float4 bx = boxes[j];
          float aj = (bx.z - bx.x) * (bx.w - bx.y);
          float yy1 = fmaxf(cy1, bx.x), xx1 = fmaxf(cx1, bx.y);
          float yy2 = fminf(cy2, bx.z), xx2 = fminf(cx2, bx.w);
          float inter = fmaxf(yy2 - yy1, 0.f) * fmaxf(xx2 - xx1, 0.f);
          float iou = inter / (((ca + aj) - inter) + 1e-9f);
          if (iou > 0.7f) { kk[j] = 0ull; k = 0ull; }
        }
      }
      if (k > bk) { bk = k; bs = j; }
    }
    #pragma unroll
    for (int off = 32; off > 0; off >>= 1) {
      unsigned long long ok_ = __shfl_down(bk, off);
      int os = __shfl_down(bs, off);
      if (ok_ > bk) { bk = ok_; bs = os; }
    }
    if ((tid & 63) == 0) { wk[tid >> 6] = bk; wslot[tid >> 6] = bs; }
    __syncthreads();
    if (tid == 0) {
      float* rp = rois + (size_t)(b * 300 + t) * 5;
      rp[0] = (float)b; rp[1] = cy1; rp[2] = cx1; rp[3] = cy2; rp[4] = cx2;
      rsc[b * 300 + t] = cs;
      unsigned long long v = wk[0]; int s = wslot[0];
      for (int k2 = 1; k2 < 8; ++k2)
        if (wk[k2] > v) { v = wk[k2]; s = wslot[k2]; }
      float4 bb = boxes[s];
      cur_s = unkey_score(v); cur_slot = s;
      cur_y1 = bb.x; cur_x1 = bb.y; cur_y2 = bb.z; cur_x2 = bb.w;
      cur_a = (bb.z - bb.x) * (bb.w - bb.y);
    }
    __syncthreads();
  }
}

// ------------------------------------------------------------------
// Diagnostic: stomps out[0] with a decodable code ONLY when clearly
// broken. absmax = s.nnnppp e+06: s 1=ok 2=ws-too-small (+4 if NaN
// scores); nnn = valid scores(batch0)/100; ppp = NMS picks(batch0).
// ------------------------------------------------------------------
__global__ void debug_kernel(const float* __restrict__ scores,
                             const float* __restrict__ out_r,
                             float* __restrict__ out, int wsflag) {
  __shared__ int s_nv, s_nn, s_pk;
  int tid = threadIdx.x;
  if (tid == 0) { s_nv = 0; s_nn = 0; s_pk = 0; }
  __syncthreads();
  int nv = 0, nn = 0;
  if (wsflag == 1) {
    for (int j = tid; j < 22500; j += 256) {
      float s = scores[j];
      if (s != s) nn++;
      else if (s > NEGH) nv++;
    }
  }
  int pk = 0;
  for (int j = tid; j < 300; j += 256)
    if (out_r[12000 + j] != 0.0f) pk++;
  atomicAdd(&s_nv, nv); atomicAdd(&s_nn, nn); atomicAdd(&s_pk, pk);
  __syncthreads();
  if (tid == 0) {
    bool bad = (wsflag != 1) || (s_nn > 0) || (s_pk == 0);
    if (bad) {
      int code = (wsflag + ((s_nn > 0) ? 4 : 0)) * 1000000
               + (s_nv / 100) * 1000 + (s_pk < 999 ? s_pk : 999);
      out[0] = (float)code;
    }
  }
}

// ------------------------------------------------------------------
extern "C" void kernel_launch(void* const* d_in, const int* in_sizes, int n_in,
                              void* d_out, int out_size, void* d_ws, size_t ws_size,
                              hipStream_t stream) {
  const float* feat = (const float*)d_in[0];
  const float* W1   = (const float*)d_in[1];
  const float* b1   = (const float*)d_in[2];
  const float* Wreg = (const float*)d_in[3];
  const float* breg = (const float*)d_in[4];
  const float* Wcls = (const float*)d_in[5];
  const float* bcls = (const float*)d_in[6];
  float* out = (float*)d_out;
  float* ws  = (float*)d_ws;

  float* conv1  = ws;              // 10,240,000 f
  float* boxes  = ws + 10240000;   //    720,000 f
  float* scores = ws + 10960000;   //    180,000 f
  float* tbx    = ws + 11140000;   //    192,000 f
  float* tsc    = ws + 11332000;   //     48,000 f
  int*   tidx   = (int*)(ws + 11380000); // 48,000 i -> total 45,712,000 B

  const int wsflag = (ws_size >= 45712000ull) ? 1 : 2;
  if (wsflag == 1) {
    conv3x3_kernel<<<dim3(20, 4, 8), 256, 0, stream>>>(feat, W1, b1, conv1);
    heads_kernel<<<5000, 256, 0, stream>>>(conv1, Wreg, breg, Wcls, bcls, boxes, scores);
    topk_kernel<<<8, 256, 0, stream>>>(scores, boxes, tsc, tbx, tidx);
    nms_kernel<<<8, 512, 0, stream>>>(tsc, tbx, tidx, out);
  }
  debug_kernel<<<1, 256, 0, stream>>>(scores, out, out, wsflag);
}